// Round 12
// baseline (373.704 us; speedup 1.0000x reference)
//
#include <hip/hip_runtime.h>
#include <hip/hip_bf16.h>
#include <hip/hip_cooperative_groups.h>

namespace cg = cooperative_groups;

typedef unsigned short u16;
typedef unsigned int   u32;

typedef __attribute__((ext_vector_type(8))) __bf16 bf16x8;
typedef __attribute__((ext_vector_type(4))) float  f32x4;
typedef __attribute__((ext_vector_type(4))) u32    u32x4;

#define NN 4096
#define DD 128
#define EPS 1e-12f

#define KS 4            // split-K factor
#define BM 32           // rows per block
#define BK 128          // k per stage
#define KPER (NN / KS)  // 1024
#define LDK 136         // padded LDS row stride (u16), 272 B (16B-aligned)
#define NZERO 2048      // att-zeroing blocks in prep (16 KB each)

static __device__ __forceinline__ u16 f2bf(float f) {
    union { float f; u32 u; } v; v.f = f;
    u32 r = v.u + 0x7fffu + ((v.u >> 16) & 1u);   // round-to-nearest-even
    return (u16)(r >> 16);
}
static __device__ __forceinline__ float bf2f(u16 u) {
    union { u32 i; float f; } v; v.i = (u32)u << 16; return v.f;
}

// --- bf16x2 atomic add: HW pk_add_bf16 if available, CAS fallback otherwise ---
template <typename T>
static __device__ __forceinline__ auto bf2_atomic_add(T* p, T v, int)
    -> decltype(unsafeAtomicAdd(p, v), void()) {
    unsafeAtomicAdd(p, v);
}
template <typename T>
static __device__ __forceinline__ void bf2_atomic_add(T* p, T v, long) {
    u32* w = (u32*)p;
    union { u32 i; T h; } av; av.h = v;
    float alo = bf2f((u16)(av.i & 0xffff));
    float ahi = bf2f((u16)(av.i >> 16));
    u32 old = *w, assumed;
    do {
        assumed = old;
        float lo = bf2f((u16)(assumed & 0xffff)) + alo;
        float hi = bf2f((u16)(assumed >> 16)) + ahi;
        u32 nv = (u32)f2bf(lo) | ((u32)f2bf(hi) << 16);
        old = atomicCAS(w, assumed, nv);
    } while (old != assumed);
}

// ---------------------------------------------------------------------------
// prep (r11 verbatim): blocks [0,128) BT1 = bf16(acts^T); rest zero att.
// ---------------------------------------------------------------------------
__global__ __launch_bounds__(256) void prep_kernel(
    const float* __restrict__ in, u16* __restrict__ out, uint4* __restrict__ attz)
{
    __shared__ __align__(16) u16 lds[128][40];
    const int t = threadIdx.x;
    if (blockIdx.x >= 128) {
        const size_t b = blockIdx.x - 128;
        uint4 z = make_uint4(0u, 0u, 0u, 0u);
#pragma unroll
        for (int i = 0; i < 4; ++i)
            attz[b * 1024 + i * 256 + t] = z;
        return;
    }
    const int k0 = blockIdx.x * 32;
#pragma unroll
    for (int i = 0; i < 4; ++i) {
        int f  = t + 256 * i;
        int kr = f >> 5;
        int n0 = (f & 31) * 4;
        float4 v = *(const float4*)(in + (size_t)(k0 + kr) * DD + n0);
        lds[n0 + 0][kr] = f2bf(v.x);
        lds[n0 + 1][kr] = f2bf(v.y);
        lds[n0 + 2][kr] = f2bf(v.z);
        lds[n0 + 3][kr] = f2bf(v.w);
    }
    __syncthreads();
    int n = t >> 1, h = t & 1;
    uint4 v0 = *(const uint4*)&lds[n][h * 16];
    uint4 v1 = *(const uint4*)&lds[n][h * 16 + 8];
    *(uint4*)(out + (size_t)n * NN + k0 + h * 16)     = v0;
    *(uint4*)(out + (size_t)n * NN + k0 + h * 16 + 8) = v1;
}

// ---------------------------------------------------------------------------
// Edge kernel (r3/r11 verbatim): 32 lanes per edge, 2 edges per wave.
// ---------------------------------------------------------------------------
__global__ __launch_bounds__(256) void edge_kernel(
    const int* __restrict__ currents, const int* __restrict__ targets,
    const float* __restrict__ A, const float* __restrict__ cases,
    u16* __restrict__ att, int E)
{
    int e = blockIdx.x * 8 + (threadIdx.x >> 5);
    if (e >= E) return;
    int l = threadIdx.x & 31;
    int c = currents[e];
    int t = targets[e];
    f32x4 h = *(const f32x4*)(A + (size_t)c * DD + l * 4);
    f32x4 g = *(const f32x4*)(A + (size_t)t * DD + l * 4);
    f32x4 q = __builtin_nontemporal_load((const f32x4*)(cases + (size_t)e * DD + l * 4));
    f32x4 d = h + q - g;
    float s = d.x * d.x + d.y * d.y + d.z * d.z + d.w * d.w;
#pragma unroll
    for (int m = 16; m; m >>= 1) s += __shfl_xor(s, m, 64);
    if (l == 0) {
        float val = __expf(-__fsqrt_rn(s));
        u16 b = f2bf(val);
        size_t off = (size_t)t * NN + c;
        union { u32 i; __hip_bfloat162 h2; } pk;
        pk.i = (c & 1) ? ((u32)b << 16) : (u32)b;
        bf2_atomic_add((__hip_bfloat162*)(att + (off & ~(size_t)1)), pk.h2, 0);
    }
}

// ---------------------------------------------------------------------------
// GEMM body (r11 gemm_splitk verbatim, flattened bid): m0=(bid&127)*BM,
// ks=bid>>7. 2-deep A prefetch / 1-deep B. Shared mem passed in.
// ---------------------------------------------------------------------------
template<bool ROWSUM, bool ABF16>
static __device__ __forceinline__ void gemm_body(
    const void* __restrict__ AmatV, const u16* __restrict__ BT,
    float* __restrict__ part, float* __restrict__ rsum_part,
    u16* As, u16* Bs)
{
    const int bid  = blockIdx.x;
    const int m0   = (bid & 127) * BM;
    const int ks   = bid >> 7;
    const int kbeg = ks * KPER;
    const int t    = threadIdx.x;
    const int wave = t >> 6;
    const int lane = t & 63;
    const int quad = lane >> 4;
    const int l16  = lane & 15;

    const int ar = t >> 4;   // 0..31 (A row)
    const int aq = t & 15;   // chunk within row
    const int bn = t >> 2;   // 0..127 (B row)
    const int bq = t & 3;    // 32-u16 chunk within row

    const float* Apf = (const float*)AmatV + (size_t)(m0 + ar) * NN + kbeg + aq * 4;
    const u16*   Aph = (const u16*)AmatV   + (size_t)(m0 + ar) * NN + kbeg + aq * 8;
    const u16*   Bp  = BT + (size_t)bn * NN + kbeg + bq * 32;

    f32x4 vaA0, vaA1, vaB0, vaB1; u32x4 vahA, vahB;
    if constexpr (ABF16) {
        vahA = __builtin_nontemporal_load((const u32x4*)Aph);
        vahB = __builtin_nontemporal_load((const u32x4*)(Aph + BK));
    } else {
        vaA0 = __builtin_nontemporal_load((const f32x4*)Apf);
        vaA1 = __builtin_nontemporal_load((const f32x4*)(Apf + 64));
        vaB0 = __builtin_nontemporal_load((const f32x4*)(Apf + BK));
        vaB1 = __builtin_nontemporal_load((const f32x4*)(Apf + BK + 64));
    }
    uint4 vb0 = *(const uint4*)(Bp);
    uint4 vb1 = *(const uint4*)(Bp + 8);
    uint4 vb2 = *(const uint4*)(Bp + 16);
    uint4 vb3 = *(const uint4*)(Bp + 24);

    f32x4 acc0 = {0.f, 0.f, 0.f, 0.f};
    f32x4 acc1 = {0.f, 0.f, 0.f, 0.f};
    float rsum = 0.f;

#define STAGE_A_BF16(VAH)                                                   \
    {                                                                       \
        if (ROWSUM) {                                                       \
            _Pragma("unroll")                                               \
            for (int j = 0; j < 4; ++j) {                                   \
                u32 w = (VAH)[j];                                           \
                rsum += bf2f((u16)(w & 0xffff)) + bf2f((u16)(w >> 16));     \
            }                                                               \
        }                                                                   \
        *(u32x4*)&As[ar * LDK + aq * 8] = (VAH);                            \
    }
#define STAGE_A_F32(V0, V1)                                                 \
    {                                                                       \
        if (ROWSUM) {                                                       \
            rsum += ((V0).x + (V0).y) + ((V0).z + (V0).w)                   \
                  + ((V1).x + (V1).y) + ((V1).z + (V1).w);                  \
        }                                                                   \
        ushort4 u0, u1;                                                     \
        u0.x = f2bf((V0).x); u0.y = f2bf((V0).y);                           \
        u0.z = f2bf((V0).z); u0.w = f2bf((V0).w);                           \
        u1.x = f2bf((V1).x); u1.y = f2bf((V1).y);                           \
        u1.z = f2bf((V1).z); u1.w = f2bf((V1).w);                           \
        *(ushort4*)&As[ar * LDK + aq * 4]      = u0;                        \
        *(ushort4*)&As[ar * LDK + aq * 4 + 64] = u1;                        \
    }
#define STAGE_B()                                                           \
    {                                                                       \
        *(uint4*)&Bs[bn * LDK + bq * 32]      = vb0;                        \
        *(uint4*)&Bs[bn * LDK + bq * 32 + 8]  = vb1;                        \
        *(uint4*)&Bs[bn * LDK + bq * 32 + 16] = vb2;                        \
        *(uint4*)&Bs[bn * LDK + bq * 32 + 24] = vb3;                        \
    }
#define LOAD_B(KOFF)                                                        \
    {                                                                       \
        vb0 = *(const uint4*)(Bp + (KOFF));                                 \
        vb1 = *(const uint4*)(Bp + (KOFF) + 8);                             \
        vb2 = *(const uint4*)(Bp + (KOFF) + 16);                            \
        vb3 = *(const uint4*)(Bp + (KOFF) + 24);                            \
    }
#define MFMA_PHASE()                                                        \
    _Pragma("unroll")                                                       \
    for (int k2 = 0; k2 < 4; ++k2) {                                        \
        bf16x8 a0 = *(const bf16x8*)&As[l16 * LDK + k2 * 32 + quad * 8];    \
        bf16x8 a1 = *(const bf16x8*)&As[(16 + l16) * LDK + k2 * 32 + quad * 8]; \
        bf16x8 b  = *(const bf16x8*)&Bs[(wave * 16 + l16) * LDK + k2 * 32 + quad * 8]; \
        acc0 = __builtin_amdgcn_mfma_f32_16x16x32_bf16(a0, b, acc0, 0, 0, 0); \
        acc1 = __builtin_amdgcn_mfma_f32_16x16x32_bf16(a1, b, acc1, 0, 0, 0); \
    }

    for (int kk = 0; kk < KPER; kk += 2 * BK) {
        if constexpr (ABF16) { STAGE_A_BF16(vahA); } else { STAGE_A_F32(vaA0, vaA1); }
        STAGE_B();
        __syncthreads();
        if (kk + 2 * BK < KPER) {
            if constexpr (ABF16) {
                vahA = __builtin_nontemporal_load((const u32x4*)(Aph + kk + 2 * BK));
            } else {
                vaA0 = __builtin_nontemporal_load((const f32x4*)(Apf + kk + 2 * BK));
                vaA1 = __builtin_nontemporal_load((const f32x4*)(Apf + kk + 2 * BK + 64));
            }
        }
        LOAD_B(kk + BK);
        MFMA_PHASE();
        __syncthreads();

        if constexpr (ABF16) { STAGE_A_BF16(vahB); } else { STAGE_A_F32(vaB0, vaB1); }
        STAGE_B();
        __syncthreads();
        if (kk + 3 * BK < KPER) {
            if constexpr (ABF16) {
                vahB = __builtin_nontemporal_load((const u32x4*)(Aph + kk + 3 * BK));
            } else {
                vaB0 = __builtin_nontemporal_load((const f32x4*)(Apf + kk + 3 * BK));
                vaB1 = __builtin_nontemporal_load((const f32x4*)(Apf + kk + 3 * BK + 64));
            }
        }
        if (kk + 2 * BK < KPER) LOAD_B(kk + 2 * BK);
        MFMA_PHASE();
        __syncthreads();
    }

    float* P = part + (size_t)ks * NN * DD;
#pragma unroll
    for (int r = 0; r < 4; ++r) {
        int row0 = m0 + quad * 4 + r;
        int col  = wave * 16 + l16;
        P[(size_t)row0 * DD + col]        = acc0[r];
        P[(size_t)(row0 + 16) * DD + col] = acc1[r];
    }

    if (ROWSUM) {
#pragma unroll
        for (int m = 8; m; m >>= 1) rsum += __shfl_xor(rsum, m, 64);
        if ((t & 15) == 0) rsum_part[ks * NN + m0 + ar] = rsum;
    }
#undef STAGE_A_BF16
#undef STAGE_A_F32
#undef STAGE_B
#undef LOAD_B
#undef MFMA_PHASE
}

// ---------------------------------------------------------------------------
// combine_feat_bt2 body (r11 verbatim; t<256 active, block b<128; lt = Bs).
// ---------------------------------------------------------------------------
static __device__ __forceinline__ void combine_bt2_body(
    const float* __restrict__ part, float* __restrict__ feat,
    u16* __restrict__ BT2, u16* ltraw)
{
    u16 (*lt)[40] = (u16(*)[40])ltraw;          // [128][40]
    const int b = blockIdx.x;
    const int t = threadIdx.x;
    const int S = NN * DD / 4;
    const int base = b * 1024;
    if (t < 256) {
#pragma unroll
        for (int it = 0; it < 4; ++it) {
            int i = base + it * 256 + t;
            const float4* p = (const float4*)part;
            float4 a = p[i], b4 = p[i + S], c = p[i + 2 * S], d = p[i + 3 * S];
            float4 s;
            s.x = (a.x + b4.x) + (c.x + d.x);
            s.y = (a.y + b4.y) + (c.y + d.y);
            s.z = (a.z + b4.z) + (c.z + d.z);
            s.w = (a.w + b4.w) + (c.w + d.w);
            ((float4*)feat)[i] = s;
            int lrow = it * 8 + (t >> 5);
            int col0 = (i & 31) * 4;
            lt[col0 + 0][lrow] = f2bf(s.x);
            lt[col0 + 1][lrow] = f2bf(s.y);
            lt[col0 + 2][lrow] = f2bf(s.z);
            lt[col0 + 3][lrow] = f2bf(s.w);
        }
    }
    __syncthreads();
    if (t < 256) {
        int col = t >> 1, half = t & 1;
        uint4 v0 = *(const uint4*)&lt[col][half * 16];
        uint4 v1 = *(const uint4*)&lt[col][half * 16 + 8];
        *(uint4*)(BT2 + (size_t)col * NN + b * 32 + half * 16)     = v0;
        *(uint4*)(BT2 + (size_t)col * NN + b * 32 + half * 16 + 8) = v1;
    }
}

// ---------------------------------------------------------------------------
// Cooperative back-chain: gemm1 | sync | combine+BT2 | sync | gemm2 | sync |
// combine_out. 512 blocks x 512 threads = 2 blocks/CU (co-residency exact).
// Replaces 4 dispatches (3 gaps) with 3 grid syncs.
// ---------------------------------------------------------------------------
__global__ __launch_bounds__(512, 4) void back_chain(
    const float* __restrict__ W,   const u16* __restrict__ BT1,
    const u16* __restrict__ att,   u16* __restrict__ BT2,
    float* __restrict__ part,      float* __restrict__ rsum_part,
    float* __restrict__ feat,      float* __restrict__ out)
{
    __shared__ __align__(16) u16 As[BM * LDK];   // 8.7 KB
    __shared__ __align__(16) u16 Bs[DD * LDK];   // 34.8 KB
    cg::grid_group grid = cg::this_grid();

    // phase 1: part = split-K partials of W @ acts
    gemm_body<false, false>(W, BT1, part, nullptr, As, Bs);
    grid.sync();

    // phase 2: feat = sum partials; BT2 = bf16(feat^T)   (blocks 0..127)
    if (blockIdx.x < 128) combine_bt2_body(part, feat, BT2, Bs);
    grid.sync();

    // phase 3: part = split-K partials of att @ feat, rsum partials
    gemm_body<true, true>(att, BT2, part, rsum_part, As, Bs);
    grid.sync();

    // phase 4: out = (sum partials)/(sum rsum + EPS) + feat
    if (threadIdx.x < 256) {
        int i = blockIdx.x * 256 + threadIdx.x;   // 512*256 = NN*DD/4
        int row = i >> 5;
        const float4* p = (const float4*)part;
        const int S = NN * DD / 4;
        float4 a = p[i], b = p[i + S], c = p[i + 2 * S], d = p[i + 3 * S];
        float ns = (rsum_part[row] + rsum_part[row + NN])
                 + (rsum_part[row + 2 * NN] + rsum_part[row + 3 * NN]);
        float sc = 1.0f / (ns + EPS);
        float4 f = ((const float4*)feat)[i];
        float4 s;
        s.x = ((a.x + b.x) + (c.x + d.x)) * sc + f.x;
        s.y = ((a.y + b.y) + (c.y + d.y)) * sc + f.y;
        s.z = ((a.z + b.z) + (c.z + d.z)) * sc + f.z;
        s.w = ((a.w + b.w) + (c.w + d.w)) * sc + f.w;
        ((float4*)out)[i] = s;
    }
}

// ---------------------------------------------------------------------------
// Fallback standalone kernels (r11 verbatim) in case cooperative launch fails.
// ---------------------------------------------------------------------------
template<bool ROWSUM, bool ABF16>
__global__ __launch_bounds__(512, 4) void gemm_splitk_fb(
    const void* __restrict__ AmatV, const u16* __restrict__ BT,
    float* __restrict__ part, float* __restrict__ rsum_part)
{
    __shared__ __align__(16) u16 As[BM * LDK];
    __shared__ __align__(16) u16 Bs[DD * LDK];
    gemm_body<ROWSUM, ABF16>(AmatV, BT, part, rsum_part, As, Bs);
}
__global__ __launch_bounds__(512) void combine_bt2_fb(
    const float* __restrict__ part, float* __restrict__ feat,
    u16* __restrict__ BT2)
{
    __shared__ __align__(16) u16 Bs[DD * LDK];
    combine_bt2_body(part, feat, BT2, Bs);
}
__global__ __launch_bounds__(256) void combine_out_fb(
    const float* __restrict__ part, const float* __restrict__ rsum_part,
    const float* __restrict__ feat, float* __restrict__ out)
{
    int i = blockIdx.x * 256 + threadIdx.x;
    int row = i >> 5;
    const float4* p = (const float4*)part;
    const int S = NN * DD / 4;
    float4 a = p[i], b = p[i + S], c = p[i + 2 * S], d = p[i + 3 * S];
    float ns = (rsum_part[row] + rsum_part[row + NN])
             + (rsum_part[row + 2 * NN] + rsum_part[row + 3 * NN]);
    float sc = 1.0f / (ns + EPS);
    float4 f = ((const float4*)feat)[i];
    float4 s;
    s.x = ((a.x + b.x) + (c.x + d.x)) * sc + f.x;
    s.y = ((a.y + b.y) + (c.y + d.y)) * sc + f.y;
    s.z = ((a.z + b.z) + (c.z + d.z)) * sc + f.z;
    s.w = ((a.w + b.w) + (c.w + d.w)) * sc + f.w;
    ((float4*)out)[i] = s;
}

// ---------------------------------------------------------------------------
extern "C" void kernel_launch(void* const* d_in, const int* in_sizes, int n_in,
                              void* d_out, int out_size, void* d_ws, size_t ws_size,
                              hipStream_t stream)
{
    const int*   currents = (const int*)d_in[0];
    const int*   targets  = (const int*)d_in[1];
    const float* acts     = (const float*)d_in[2];   // [4096][128]
    const float* cases    = (const float*)d_in[3];   // [E][128]
    const float* W        = (const float*)d_in[4];   // [4096][4096]
    float*       out      = (float*)d_out;           // [4096][128]
    const int E = in_sizes[0];

    // workspace layout
    char* ws = (char*)d_ws;
    u16*   att       = (u16*)ws;                                     // 32 MB (bf16)
    float* part      = (float*)(ws + (size_t)NN * NN * 2);           // KS*2 MB
    float* feat      = part + (size_t)KS * NN * DD;                  // 2 MB
    u16*   BT1       = (u16*)(feat + (size_t)NN * DD);               // 1 MB
    u16*   BT2       = BT1 + (size_t)DD * NN;                        // 1 MB
    float* rsum_part = (float*)(BT2 + (size_t)DD * NN);              // 64 KB

    // 1. prep: BT1 = bf16(acts^T)  ||  att = 0
    prep_kernel<<<128 + NZERO, 256, 0, stream>>>(acts, BT1, (uint4*)att);

    // 2. edge scatter
    edge_kernel<<<(E + 7) / 8, 256, 0, stream>>>(currents, targets, acts, cases,
                                                 att, E);

    // 3. cooperative back-chain (gemm1 + combine + gemm2 + combine_out)
    const float* Wa = W; const u16* BT1a = BT1; const u16* atta = att;
    u16* BT2a = BT2; float* parta = part; float* rsa = rsum_part;
    float* feata = feat; float* outa = out;
    void* args[] = { (void*)&Wa, (void*)&BT1a, (void*)&atta, (void*)&BT2a,
                     (void*)&parta, (void*)&rsa, (void*)&feata, (void*)&outa };
    hipError_t err = hipLaunchCooperativeKernel(
        (const void*)back_chain, dim3(512), dim3(512), args, 0, stream);
    if (err != hipSuccess) {
        // fallback: r11 dispatch sequence
        gemm_splitk_fb<false, false><<<512, 512, 0, stream>>>(W, BT1, part, nullptr);
        combine_bt2_fb<<<128, 512, 0, stream>>>(part, feat, BT2);
        gemm_splitk_fb<true, true><<<512, 512, 0, stream>>>(att, BT2, part, rsum_part);
        combine_out_fb<<<NN * DD / 4 / 256, 256, 0, stream>>>(part, rsum_part, feat, out);
    }
}

// Round 13
// 185.340 us; speedup vs baseline: 2.0163x; 2.0163x over previous
//
#include <hip/hip_runtime.h>
#include <hip/hip_bf16.h>

typedef unsigned short u16;
typedef unsigned int   u32;

typedef __attribute__((ext_vector_type(8))) __bf16 bf16x8;
typedef __attribute__((ext_vector_type(4))) float  f32x4;
typedef __attribute__((ext_vector_type(4))) u32    u32x4;

#define NN 4096
#define DD 128
#define EPS 1e-12f

#define KS 4            // split-K factor
#define BM 32           // rows per block
#define BK 128          // k per stage
#define KPER (NN / KS)  // 1024
#define LDK 136         // padded LDS row stride (u16), 272 B (16B-aligned)
#define NZERO 2048      // att-zeroing blocks in prep (16 KB each)

static __device__ __forceinline__ u16 f2bf(float f) {
    union { float f; u32 u; } v; v.f = f;
    u32 r = v.u + 0x7fffu + ((v.u >> 16) & 1u);   // round-to-nearest-even
    return (u16)(r >> 16);
}
static __device__ __forceinline__ float bf2f(u16 u) {
    union { u32 i; float f; } v; v.i = (u32)u << 16; return v.f;
}

// --- bf16x2 atomic add: HW pk_add_bf16 if available, CAS fallback otherwise ---
template <typename T>
static __device__ __forceinline__ auto bf2_atomic_add(T* p, T v, int)
    -> decltype(unsafeAtomicAdd(p, v), void()) {
    unsafeAtomicAdd(p, v);
}
template <typename T>
static __device__ __forceinline__ void bf2_atomic_add(T* p, T v, long) {
    u32* w = (u32*)p;
    union { u32 i; T h; } av; av.h = v;
    float alo = bf2f((u16)(av.i & 0xffff));
    float ahi = bf2f((u16)(av.i >> 16));
    u32 old = *w, assumed;
    do {
        assumed = old;
        float lo = bf2f((u16)(assumed & 0xffff)) + alo;
        float hi = bf2f((u16)(assumed >> 16)) + ahi;
        u32 nv = (u32)f2bf(lo) | ((u32)f2bf(hi) << 16);
        old = atomicCAS(w, assumed, nv);
    } while (old != assumed);
}

// ---------------------------------------------------------------------------
// prep: block-role split. Blocks [0,128): BT1 = bf16(acts^T). Blocks
// [128, 128+NZERO): zero 16 KB of att each (replaces fillBuffer dispatch).
// ---------------------------------------------------------------------------
__global__ __launch_bounds__(256) void prep_kernel(
    const float* __restrict__ in, u16* __restrict__ out, uint4* __restrict__ attz)
{
    __shared__ __align__(16) u16 lds[128][40];
    const int t = threadIdx.x;
    if (blockIdx.x >= 128) {
        const size_t b = blockIdx.x - 128;
        uint4 z = make_uint4(0u, 0u, 0u, 0u);
#pragma unroll
        for (int i = 0; i < 4; ++i)
            attz[b * 1024 + i * 256 + t] = z;
        return;
    }
    const int k0 = blockIdx.x * 32;
#pragma unroll
    for (int i = 0; i < 4; ++i) {
        int f  = t + 256 * i;
        int kr = f >> 5;
        int n0 = (f & 31) * 4;
        float4 v = *(const float4*)(in + (size_t)(k0 + kr) * DD + n0);
        lds[n0 + 0][kr] = f2bf(v.x);
        lds[n0 + 1][kr] = f2bf(v.y);
        lds[n0 + 2][kr] = f2bf(v.z);
        lds[n0 + 3][kr] = f2bf(v.w);
    }
    __syncthreads();
    int n = t >> 1, h = t & 1;
    uint4 v0 = *(const uint4*)&lds[n][h * 16];
    uint4 v1 = *(const uint4*)&lds[n][h * 16 + 8];
    *(uint4*)(out + (size_t)n * NN + k0 + h * 16)     = v0;
    *(uint4*)(out + (size_t)n * NN + k0 + h * 16 + 8) = v1;
}

// ---------------------------------------------------------------------------
// Edge kernel: 32 lanes per edge, 2 edges per wave. Packed-bf16 atomic.
// ---------------------------------------------------------------------------
__global__ __launch_bounds__(256) void edge_kernel(
    const int* __restrict__ currents, const int* __restrict__ targets,
    const float* __restrict__ A, const float* __restrict__ cases,
    u16* __restrict__ att, int E)
{
    int e = blockIdx.x * 8 + (threadIdx.x >> 5);
    if (e >= E) return;
    int l = threadIdx.x & 31;
    int c = currents[e];
    int t = targets[e];
    f32x4 h = *(const f32x4*)(A + (size_t)c * DD + l * 4);
    f32x4 g = *(const f32x4*)(A + (size_t)t * DD + l * 4);
    f32x4 q = __builtin_nontemporal_load((const f32x4*)(cases + (size_t)e * DD + l * 4));
    f32x4 d = h + q - g;
    float s = d.x * d.x + d.y * d.y + d.z * d.z + d.w * d.w;
#pragma unroll
    for (int m = 16; m; m >>= 1) s += __shfl_xor(s, m, 64);
    if (l == 0) {
        float val = __expf(-__fsqrt_rn(s));
        u16 b = f2bf(val);
        size_t off = (size_t)t * NN + c;
        union { u32 i; __hip_bfloat162 h2; } pk;
        pk.i = (c & 1) ? ((u32)b << 16) : (u32)b;
        bf2_atomic_add((__hip_bfloat162*)(att + (off & ~(size_t)1)), pk.h2, 0);
    }
}

// ---------------------------------------------------------------------------
// Split-K skinny GEMM, 2-deep A-prefetch / 1-deep B-prefetch:
//   part[ks] = Amat[m0:m0+32, ks*1024:(ks+1)*1024] @ B
// ROWSUM: per-block row-sums written NON-atomically to rsum_part[ks][row].
// ---------------------------------------------------------------------------
template<bool ROWSUM, bool ABF16>
__global__ __launch_bounds__(512, 4) void gemm_splitk(
    const void* __restrict__ AmatV,
    const u16*  __restrict__ BT,      // [128][4096] bf16 (B^T)
    float* __restrict__ part,         // [KS][4096][128]
    float* __restrict__ rsum_part)    // [KS][4096] (ROWSUM only)
{
    __shared__ __align__(16) u16 As[BM * LDK];   // 8.7 KB
    __shared__ __align__(16) u16 Bs[DD * LDK];   // 34.8 KB

    const int m0   = blockIdx.x * BM;
    const int ks   = blockIdx.y;
    const int kbeg = ks * KPER;
    const int t    = threadIdx.x;
    const int wave = t >> 6;
    const int lane = t & 63;
    const int quad = lane >> 4;
    const int l16  = lane & 15;

    const int ar = t >> 4;   // 0..31 (A row)
    const int aq = t & 15;   // chunk within row
    const int bn = t >> 2;   // 0..127 (B row)
    const int bq = t & 3;    // 32-u16 chunk within row

    const float* Apf = (const float*)AmatV + (size_t)(m0 + ar) * NN + kbeg + aq * 4;
    const u16*   Aph = (const u16*)AmatV   + (size_t)(m0 + ar) * NN + kbeg + aq * 8;
    const u16*   Bp  = BT + (size_t)bn * NN + kbeg + bq * 32;

    // prologue: A tiles 0 and 1 (2-deep), B tile 0 (1-deep)
    f32x4 vaA0, vaA1, vaB0, vaB1; u32x4 vahA, vahB;
    if constexpr (ABF16) {
        vahA = __builtin_nontemporal_load((const u32x4*)Aph);
        vahB = __builtin_nontemporal_load((const u32x4*)(Aph + BK));
    } else {
        vaA0 = __builtin_nontemporal_load((const f32x4*)Apf);
        vaA1 = __builtin_nontemporal_load((const f32x4*)(Apf + 64));
        vaB0 = __builtin_nontemporal_load((const f32x4*)(Apf + BK));
        vaB1 = __builtin_nontemporal_load((const f32x4*)(Apf + BK + 64));
    }
    uint4 vb0 = *(const uint4*)(Bp);
    uint4 vb1 = *(const uint4*)(Bp + 8);
    uint4 vb2 = *(const uint4*)(Bp + 16);
    uint4 vb3 = *(const uint4*)(Bp + 24);

    f32x4 acc0 = {0.f, 0.f, 0.f, 0.f};
    f32x4 acc1 = {0.f, 0.f, 0.f, 0.f};
    float rsum = 0.f;

#define STAGE_A_BF16(VAH)                                                   \
    {                                                                       \
        if (ROWSUM) {                                                       \
            _Pragma("unroll")                                               \
            for (int j = 0; j < 4; ++j) {                                   \
                u32 w = (VAH)[j];                                           \
                rsum += bf2f((u16)(w & 0xffff)) + bf2f((u16)(w >> 16));     \
            }                                                               \
        }                                                                   \
        *(u32x4*)&As[ar * LDK + aq * 8] = (VAH);                            \
    }
#define STAGE_A_F32(V0, V1)                                                 \
    {                                                                       \
        if (ROWSUM) {                                                       \
            rsum += ((V0).x + (V0).y) + ((V0).z + (V0).w)                   \
                  + ((V1).x + (V1).y) + ((V1).z + (V1).w);                  \
        }                                                                   \
        ushort4 u0, u1;                                                     \
        u0.x = f2bf((V0).x); u0.y = f2bf((V0).y);                           \
        u0.z = f2bf((V0).z); u0.w = f2bf((V0).w);                           \
        u1.x = f2bf((V1).x); u1.y = f2bf((V1).y);                           \
        u1.z = f2bf((V1).z); u1.w = f2bf((V1).w);                           \
        *(ushort4*)&As[ar * LDK + aq * 4]      = u0;                        \
        *(ushort4*)&As[ar * LDK + aq * 4 + 64] = u1;                        \
    }
#define STAGE_B()                                                           \
    {                                                                       \
        *(uint4*)&Bs[bn * LDK + bq * 32]      = vb0;                        \
        *(uint4*)&Bs[bn * LDK + bq * 32 + 8]  = vb1;                        \
        *(uint4*)&Bs[bn * LDK + bq * 32 + 16] = vb2;                        \
        *(uint4*)&Bs[bn * LDK + bq * 32 + 24] = vb3;                        \
    }
#define LOAD_B(KOFF)                                                        \
    {                                                                       \
        vb0 = *(const uint4*)(Bp + (KOFF));                                 \
        vb1 = *(const uint4*)(Bp + (KOFF) + 8);                             \
        vb2 = *(const uint4*)(Bp + (KOFF) + 16);                            \
        vb3 = *(const uint4*)(Bp + (KOFF) + 24);                            \
    }
#define MFMA_PHASE()                                                        \
    _Pragma("unroll")                                                       \
    for (int k2 = 0; k2 < 4; ++k2) {                                        \
        bf16x8 a0 = *(const bf16x8*)&As[l16 * LDK + k2 * 32 + quad * 8];    \
        bf16x8 a1 = *(const bf16x8*)&As[(16 + l16) * LDK + k2 * 32 + quad * 8]; \
        bf16x8 b  = *(const bf16x8*)&Bs[(wave * 16 + l16) * LDK + k2 * 32 + quad * 8]; \
        acc0 = __builtin_amdgcn_mfma_f32_16x16x32_bf16(a0, b, acc0, 0, 0, 0); \
        acc1 = __builtin_amdgcn_mfma_f32_16x16x32_bf16(a1, b, acc1, 0, 0, 0); \
    }

    for (int kk = 0; kk < KPER; kk += 2 * BK) {
        // ---------------- half 1: data kk (A set A) ----------------
        if constexpr (ABF16) { STAGE_A_BF16(vahA); } else { STAGE_A_F32(vaA0, vaA1); }
        STAGE_B();
        __syncthreads();
        if (kk + 2 * BK < KPER) {
            if constexpr (ABF16) {
                vahA = __builtin_nontemporal_load((const u32x4*)(Aph + kk + 2 * BK));
            } else {
                vaA0 = __builtin_nontemporal_load((const f32x4*)(Apf + kk + 2 * BK));
                vaA1 = __builtin_nontemporal_load((const f32x4*)(Apf + kk + 2 * BK + 64));
            }
        }
        LOAD_B(kk + BK);   // kk+BK < KPER always (KPER multiple of 2*BK)
        MFMA_PHASE();
        __syncthreads();

        // ---------------- half 2: data kk+BK (A set B) ----------------
        if constexpr (ABF16) { STAGE_A_BF16(vahB); } else { STAGE_A_F32(vaB0, vaB1); }
        STAGE_B();
        __syncthreads();
        if (kk + 3 * BK < KPER) {
            if constexpr (ABF16) {
                vahB = __builtin_nontemporal_load((const u32x4*)(Aph + kk + 3 * BK));
            } else {
                vaB0 = __builtin_nontemporal_load((const f32x4*)(Apf + kk + 3 * BK));
                vaB1 = __builtin_nontemporal_load((const f32x4*)(Apf + kk + 3 * BK + 64));
            }
        }
        if (kk + 2 * BK < KPER) LOAD_B(kk + 2 * BK);
        MFMA_PHASE();
        __syncthreads();
    }

    // D layout: col = lane&15 (within wave's 16-col tile), row = quad*4+reg
    float* P = part + (size_t)ks * NN * DD;
#pragma unroll
    for (int r = 0; r < 4; ++r) {
        int row0 = m0 + quad * 4 + r;
        int col  = wave * 16 + l16;
        P[(size_t)row0 * DD + col]        = acc0[r];
        P[(size_t)(row0 + 16) * DD + col] = acc1[r];
    }

    if (ROWSUM) {
#pragma unroll
        for (int m = 8; m; m >>= 1) rsum += __shfl_xor(rsum, m, 64);
        if ((t & 15) == 0) rsum_part[ks * NN + m0 + ar] = rsum;
    }
#undef STAGE_A_BF16
#undef STAGE_A_F32
#undef STAGE_B
#undef LOAD_B
#undef MFMA_PHASE
}

// ---------------------------------------------------------------------------
// combine_feat + transpose2 fused: feat = sum of KS partials,
// BT2 = bf16(feat^T) via LDS transpose. Block b handles 32 rows.
// ---------------------------------------------------------------------------
__global__ __launch_bounds__(256) void combine_feat_bt2(
    const float* __restrict__ part, float* __restrict__ feat,
    u16* __restrict__ BT2)
{
    __shared__ __align__(16) u16 lt[128][40];   // [col][row 0..31, pad->40]
    const int b = blockIdx.x;                   // 128 blocks, rows 32b..32b+31
    const int t = threadIdx.x;
    const int S = NN * DD / 4;
    const int base = b * 1024;                  // f4 index of row 32b, col 0
#pragma unroll
    for (int it = 0; it < 4; ++it) {
        int i = base + it * 256 + t;
        const float4* p = (const float4*)part;
        float4 a = p[i], b4 = p[i + S], c = p[i + 2 * S], d = p[i + 3 * S];
        float4 s;
        s.x = (a.x + b4.x) + (c.x + d.x);
        s.y = (a.y + b4.y) + (c.y + d.y);
        s.z = (a.z + b4.z) + (c.z + d.z);
        s.w = (a.w + b4.w) + (c.w + d.w);
        ((float4*)feat)[i] = s;
        int lrow = it * 8 + (t >> 5);           // 0..31
        int col0 = (i & 31) * 4;
        lt[col0 + 0][lrow] = f2bf(s.x);
        lt[col0 + 1][lrow] = f2bf(s.y);
        lt[col0 + 2][lrow] = f2bf(s.z);
        lt[col0 + 3][lrow] = f2bf(s.w);
    }
    __syncthreads();
    int col = t >> 1, half = t & 1;             // 16 rows (32B) per thread
    uint4 v0 = *(const uint4*)&lt[col][half * 16];
    uint4 v1 = *(const uint4*)&lt[col][half * 16 + 8];
    *(uint4*)(BT2 + (size_t)col * NN + b * 32 + half * 16)     = v0;
    *(uint4*)(BT2 + (size_t)col * NN + b * 32 + half * 16 + 8) = v1;
}

// ---------------------------------------------------------------------------
// out = (sum of KS partials) / (sum of KS rsum partials + EPS) + feat
// ---------------------------------------------------------------------------
__global__ __launch_bounds__(256) void combine_out(
    const float* __restrict__ part, const float* __restrict__ rsum_part,
    const float* __restrict__ feat, float* __restrict__ out)
{
    int i = blockIdx.x * 256 + threadIdx.x;   // float4 index
    int row = i >> 5;                          // 32 float4 per 128-col row
    const float4* p = (const float4*)part;
    const int S = NN * DD / 4;
    float4 a = p[i], b = p[i + S], c = p[i + 2 * S], d = p[i + 3 * S];
    float ns = (rsum_part[row] + rsum_part[row + NN])
             + (rsum_part[row + 2 * NN] + rsum_part[row + 3 * NN]);
    float sc = 1.0f / (ns + EPS);
    float4 f = ((const float4*)feat)[i];
    float4 s;
    s.x = ((a.x + b.x) + (c.x + d.x)) * sc + f.x;
    s.y = ((a.y + b.y) + (c.y + d.y)) * sc + f.y;
    s.z = ((a.z + b.z) + (c.z + d.z)) * sc + f.z;
    s.w = ((a.w + b.w) + (c.w + d.w)) * sc + f.w;
    ((float4*)out)[i] = s;
}

// ---------------------------------------------------------------------------
extern "C" void kernel_launch(void* const* d_in, const int* in_sizes, int n_in,
                              void* d_out, int out_size, void* d_ws, size_t ws_size,
                              hipStream_t stream)
{
    const int*   currents = (const int*)d_in[0];
    const int*   targets  = (const int*)d_in[1];
    const float* acts     = (const float*)d_in[2];   // [4096][128]
    const float* cases    = (const float*)d_in[3];   // [E][128]
    const float* W        = (const float*)d_in[4];   // [4096][4096]
    float*       out      = (float*)d_out;           // [4096][128]
    const int E = in_sizes[0];

    // workspace layout
    char* ws = (char*)d_ws;
    u16*   att       = (u16*)ws;                                     // 32 MB (bf16)
    float* part      = (float*)(ws + (size_t)NN * NN * 2);           // KS*2 MB
    float* feat      = part + (size_t)KS * NN * DD;                  // 2 MB
    u16*   BT1       = (u16*)(feat + (size_t)NN * DD);               // 1 MB
    u16*   BT2       = BT1 + (size_t)DD * NN;                        // 1 MB
    float* rsum_part = (float*)(BT2 + (size_t)DD * NN);              // 64 KB

    // 1. prep: BT1 = bf16(acts^T)  ||  att = 0  (fillBuffer dispatch removed)
    prep_kernel<<<128 + NZERO, 256, 0, stream>>>(acts, BT1, (uint4*)att);

    // 2. edge scatter
    edge_kernel<<<(E + 7) / 8, 256, 0, stream>>>(currents, targets, acts, cases,
                                                 att, E);

    // 3. feat = W @ acts  (2-deep A prefetch), + BT2 in the combine epilogue
    gemm_splitk<false, false><<<dim3(NN / BM, KS), 512, 0, stream>>>(W, BT1, part, nullptr);
    combine_feat_bt2<<<128, 256, 0, stream>>>(part, feat, BT2);

    // 4. out = (att @ feat) / norm + feat  (gemm2 writes non-atomic rsum partials)
    gemm_splitk<true, true><<<dim3(NN / BM, KS), 512, 0, stream>>>(att, BT2, part, rsum_part);
    combine_out<<<NN * DD / 4 / 256, 256, 0, stream>>>(part, rsum_part, feat, out);
}